// Round 3
// baseline (1292.803 us; speedup 1.0000x reference)
//
#include <hip/hip_runtime.h>
#include <hip/hip_bf16.h>
#include <cstdint>

#define DIM_   1024
#define H_     16
#define DH_    64
#define INNER_ 1024
#define B_     2
#define I_     2048
#define J_     2048
#define SCALE_ 0.125f

using bf16x8 = __attribute__((ext_vector_type(8))) short;
using f32x4  = __attribute__((ext_vector_type(4))) float;
using f32x2  = __attribute__((ext_vector_type(2))) float;

__device__ __forceinline__ unsigned short f2bf(float f) {
  unsigned int u = __float_as_uint(f);
  u = (u + 0x7FFFu + ((u >> 16) & 1u)) >> 16;
  return (unsigned short)u;
}

// ---------------- LayerNorm + cast to bf16 ----------------
__global__ __launch_bounds__(256) void ln_cast_kernel(
    const float* __restrict__ in, const float* __restrict__ g,
    const float* __restrict__ bb, unsigned short* __restrict__ out) {
  int row = blockIdx.x;
  int t = threadIdx.x;
  const float4* rp = (const float4*)(in + (size_t)row * DIM_);
  float4 v = rp[t];
  float s  = v.x + v.y + v.z + v.w;
  float ss = v.x * v.x + v.y * v.y + v.z * v.z + v.w * v.w;
  for (int o = 1; o < 64; o <<= 1) {
    s  += __shfl_xor(s, o, 64);
    ss += __shfl_xor(ss, o, 64);
  }
  __shared__ float ls[4], lss[4];
  int wave = t >> 6, lane = t & 63;
  if (lane == 0) { ls[wave] = s; lss[wave] = ss; }
  __syncthreads();
  s  = ls[0] + ls[1] + ls[2] + ls[3];
  ss = lss[0] + lss[1] + lss[2] + lss[3];
  float mu  = s * (1.0f / DIM_);
  float var = ss * (1.0f / DIM_) - mu * mu;
  float rstd = rsqrtf(var + 1e-5f);
  float4 gv = ((const float4*)g)[t];
  float4 bv = ((const float4*)bb)[t];
  ushort4 o4;
  o4.x = f2bf((v.x - mu) * rstd * gv.x + bv.x);
  o4.y = f2bf((v.y - mu) * rstd * gv.y + bv.y);
  o4.z = f2bf((v.z - mu) * rstd * gv.z + bv.z);
  o4.w = f2bf((v.w - mu) * rstd * gv.w + bv.w);
  ((ushort4*)(out + (size_t)row * DIM_))[t] = o4;
}

// ---------------- transpose + cast f32 -> bf16 ----------------
__global__ __launch_bounds__(256) void transpose_cast_f32(
    const float* __restrict__ in, unsigned short* __restrict__ out, int R, int C) {
  __shared__ float tile[32][33];
  int z = blockIdx.z;
  const float* ip = in + (size_t)z * R * C;
  unsigned short* op = out + (size_t)z * R * C;
  int c0 = blockIdx.x * 32, r0 = blockIdx.y * 32;
  int tx = threadIdx.x, ty = threadIdx.y;
  for (int k = 0; k < 4; k++)
    tile[ty * 4 + k][tx] = ip[(size_t)(r0 + ty * 4 + k) * C + c0 + tx];
  __syncthreads();
  for (int k = 0; k < 4; k++)
    op[(size_t)(c0 + ty * 4 + k) * R + r0 + tx] = f2bf(tile[tx][ty * 4 + k]);
}

// ---------------- transpose bf16 -> bf16 ----------------
__global__ __launch_bounds__(256) void transpose_bf16(
    const unsigned short* __restrict__ in, unsigned short* __restrict__ out, int R, int C) {
  __shared__ unsigned short tile[32][33];
  int z = blockIdx.z;
  const unsigned short* ip = in + (size_t)z * R * C;
  unsigned short* op = out + (size_t)z * R * C;
  int c0 = blockIdx.x * 32, r0 = blockIdx.y * 32;
  int tx = threadIdx.x, ty = threadIdx.y;
  for (int k = 0; k < 4; k++)
    tile[ty * 4 + k][tx] = ip[(size_t)(r0 + ty * 4 + k) * C + c0 + tx];
  __syncthreads();
  for (int k = 0; k < 4; k++)
    op[(size_t)(c0 + ty * 4 + k) * R + r0 + tx] = tile[tx][ty * 4 + k];
}

// ---------------- bf16 GEMM: C[M,N] = A[M,K] @ Bt[N,K]^T (+bias) ----------------
#define LDP 40
__global__ __launch_bounds__(256) void gemm_bt(
    const unsigned short* __restrict__ A, const unsigned short* __restrict__ Bt,
    const float* __restrict__ bias, void* __restrict__ Cout,
    int M, int N, int K, int c_f32) {
  __shared__ unsigned short As[128 * LDP];
  __shared__ unsigned short Bs[128 * LDP];
  int t = threadIdx.x;
  int lane = t & 63, wave = t >> 6;
  int m0 = blockIdx.y * 128, n0 = blockIdx.x * 128;
  int wm = (wave >> 1) * 64, wn = (wave & 1) * 64;
  int l15 = lane & 15, lk = lane >> 4;
  int lrow = t >> 2, lc8 = (t & 3) * 8;
  f32x4 acc[4][4] = {};

  for (int k0 = 0; k0 < K; k0 += 32) {
    *(bf16x8*)&As[lrow * LDP + lc8]        = *(const bf16x8*)&A[(size_t)(m0 + lrow) * K + k0 + lc8];
    *(bf16x8*)&As[(lrow + 64) * LDP + lc8] = *(const bf16x8*)&A[(size_t)(m0 + lrow + 64) * K + k0 + lc8];
    *(bf16x8*)&Bs[lrow * LDP + lc8]        = *(const bf16x8*)&Bt[(size_t)(n0 + lrow) * K + k0 + lc8];
    *(bf16x8*)&Bs[(lrow + 64) * LDP + lc8] = *(const bf16x8*)&Bt[(size_t)(n0 + lrow + 64) * K + k0 + lc8];
    __syncthreads();
    bf16x8 af[4], bfr[4];
#pragma unroll
    for (int mi = 0; mi < 4; mi++) af[mi]  = *(const bf16x8*)&As[(wm + mi * 16 + l15) * LDP + lk * 8];
#pragma unroll
    for (int ni = 0; ni < 4; ni++) bfr[ni] = *(const bf16x8*)&Bs[(wn + ni * 16 + l15) * LDP + lk * 8];
#pragma unroll
    for (int mi = 0; mi < 4; mi++)
#pragma unroll
      for (int ni = 0; ni < 4; ni++)
        acc[mi][ni] = __builtin_amdgcn_mfma_f32_16x16x32_bf16(af[mi], bfr[ni], acc[mi][ni], 0, 0, 0);
    __syncthreads();
  }
#pragma unroll
  for (int mi = 0; mi < 4; mi++)
#pragma unroll
    for (int ni = 0; ni < 4; ni++) {
      int col = n0 + wn + ni * 16 + l15;
      float bsv = bias ? bias[col] : 0.0f;
#pragma unroll
      for (int r = 0; r < 4; r++) {
        int row = m0 + wm + mi * 16 + lk * 4 + r;
        float val = acc[mi][ni][r] + bsv;
        if (c_f32) ((float*)Cout)[(size_t)row * N + col] = val;
        else ((unsigned short*)Cout)[(size_t)row * N + col] = f2bf(val);
      }
    }
}

// ---------------- stats: rsum[b,h,i] = sum_j exp(SCALE * dot(...)) ----------------
__global__ __launch_bounds__(256) void stats_kernel(
    const unsigned short* __restrict__ Q, const unsigned short* __restrict__ Kc,
    float* __restrict__ rsum, int NQ, int NK) {
  int b = blockIdx.z, h = blockIdx.y, i0 = blockIdx.x * 32;
  int t = threadIdx.x, lane = t & 63, wave = t >> 6;
  int l15 = lane & 15, lk = lane >> 4;
  const size_t qbase = ((size_t)b * NQ + i0) * INNER_ + h * DH_;
  bf16x8 af[2][2];
#pragma unroll
  for (int mi = 0; mi < 2; mi++)
#pragma unroll
    for (int ks = 0; ks < 2; ks++)
      af[mi][ks] = *(const bf16x8*)&Q[qbase + (size_t)(mi * 16 + l15) * INNER_ + ks * 32 + lk * 8];
  float racc[2][4] = {};
  for (int j0 = wave * 16; j0 < NK; j0 += 64) {
    const size_t kbase = ((size_t)b * NK + j0 + l15) * INNER_ + h * DH_ + lk * 8;
    bf16x8 b0 = *(const bf16x8*)&Kc[kbase];
    bf16x8 b1 = *(const bf16x8*)&Kc[kbase + 32];
#pragma unroll
    for (int mi = 0; mi < 2; mi++) {
      f32x4 acc = {};
      acc = __builtin_amdgcn_mfma_f32_16x16x32_bf16(af[mi][0], b0, acc, 0, 0, 0);
      acc = __builtin_amdgcn_mfma_f32_16x16x32_bf16(af[mi][1], b1, acc, 0, 0, 0);
#pragma unroll
      for (int r = 0; r < 4; r++) racc[mi][r] += __expf(acc[r] * SCALE_);
    }
  }
#pragma unroll
  for (int o = 1; o < 16; o <<= 1)
#pragma unroll
    for (int mi = 0; mi < 2; mi++)
#pragma unroll
      for (int r = 0; r < 4; r++) racc[mi][r] += __shfl_xor(racc[mi][r], o, 64);
  __shared__ float part[4][32];
  if (l15 == 0)
#pragma unroll
    for (int mi = 0; mi < 2; mi++)
#pragma unroll
      for (int r = 0; r < 4; r++) part[wave][mi * 16 + lk * 4 + r] = racc[mi][r];
  __syncthreads();
  if (t < 32)
    rsum[((size_t)b * H_ + h) * NQ + i0 + t] = part[0][t] + part[1][t] + part[2][t] + part[3][t];
}

// ---------------- mix kernel: sim tile once -> M1[g,i,j], M2[g,j,i] ----------------
// grid (CJ/64, I/16, B), 256 thr, 4 waves. Wave w: j-strip w*16 of the block's
// 64-j group. Pass1: A=K,B=Q -> thread (i=l15 fixed, j=lk*4+r). Pass2 swapped ->
// thread (j=l15 fixed, i=lk*4+r). No LDS round trip, no barriers after preload.
__global__ __launch_bounds__(256) void mix_kernel(
    const unsigned short* __restrict__ Q, const unsigned short* __restrict__ Kc,
    const float* __restrict__ rsum, const float* __restrict__ csum,
    const float* __restrict__ thw, const float* __restrict__ cthw,
    unsigned short* __restrict__ M1, unsigned short* __restrict__ M2,
    int chunk_base, int CJ) {
  __shared__ float rinvS[256];    // [h][i 16]
  __shared__ float cinvS[1024];   // [h][j 64]
  int jx = blockIdx.x, ib = blockIdx.y, b = blockIdx.z;
  int i0 = ib * 16;
  int jg0 = chunk_base + jx * 64;   // global j base of this block
  int jl0 = jx * 64;                // chunk-local j base
  int t = threadIdx.x, lane = t & 63, wave = t >> 6;
  int l15 = lane & 15, lk = lane >> 4;

  rinvS[t] = 1.0f / rsum[((size_t)b * H_ + (t >> 4)) * I_ + i0 + (t & 15)];
  {
    int h4 = t >> 4, j4 = (t & 15) * 4;
    float4 cv4 = *(const float4*)&csum[((size_t)b * H_ + h4) * J_ + jg0 + j4];
    cinvS[h4 * 64 + j4 + 0] = 1.0f / cv4.x;
    cinvS[h4 * 64 + j4 + 1] = 1.0f / cv4.y;
    cinvS[h4 * 64 + j4 + 2] = 1.0f / cv4.z;
    cinvS[h4 * 64 + j4 + 3] = 1.0f / cv4.w;
  }
  __syncthreads();

  const unsigned short* Qr = Q + ((size_t)b * I_ + i0 + l15) * INNER_;       // row i0+l15
  const unsigned short* Kr = Kc + ((size_t)b * J_ + jg0 + wave * 16 + l15) * INNER_; // row j

  f32x4 s[16];

  // ---- pass 1: sim with A=K (m=j), B=Q (n=i) ----
#pragma unroll
  for (int h = 0; h < H_; h++) {
    bf16x8 ka0 = *(const bf16x8*)&Kr[h * 64 + lk * 8];
    bf16x8 ka1 = *(const bf16x8*)&Kr[h * 64 + 32 + lk * 8];
    bf16x8 qb0 = *(const bf16x8*)&Qr[h * 64 + lk * 8];
    bf16x8 qb1 = *(const bf16x8*)&Qr[h * 64 + 32 + lk * 8];
    f32x4 a = {};
    a = __builtin_amdgcn_mfma_f32_16x16x32_bf16(ka0, qb0, a, 0, 0, 0);
    a = __builtin_amdgcn_mfma_f32_16x16x32_bf16(ka1, qb1, a, 0, 0, 0);
    s[h] = a;
  }
  // dir1 probs in place: thread i = i0+l15 (fixed), j = jg0+wave*16+lk*4+r
#pragma unroll
  for (int h = 0; h < H_; h++) {
    float ri = rinvS[h * 16 + l15];
#pragma unroll
    for (int r = 0; r < 4; r++) s[h][r] = __expf(s[h][r] * SCALE_) * ri;
  }
  // mix + write M1[bg][i][j-local] (b64 per g)
#pragma unroll
  for (int g = 0; g < H_; g++) {
    f32x2 mlo = {0.f, 0.f}, mhi = {0.f, 0.f};
#pragma unroll
    for (int h = 0; h < H_; h++) {
      float w = thw[g * H_ + h];   // uniform -> s_load
      f32x2 slo = {s[h][0], s[h][1]};
      f32x2 shi = {s[h][2], s[h][3]};
      mlo += w * slo;
      mhi += w * shi;
    }
    ushort4 o;
    o.x = f2bf(mlo[0]); o.y = f2bf(mlo[1]); o.z = f2bf(mhi[0]); o.w = f2bf(mhi[1]);
    *(ushort4*)&M1[(((size_t)b * H_ + g) * I_ + i0 + l15) * CJ + jl0 + wave * 16 + lk * 4] = o;
  }

  // ---- pass 2: sim^T with A=Q (m=i), B=K (n=j) ----
#pragma unroll
  for (int h = 0; h < H_; h++) {
    bf16x8 qa0 = *(const bf16x8*)&Qr[h * 64 + lk * 8];
    bf16x8 qa1 = *(const bf16x8*)&Qr[h * 64 + 32 + lk * 8];
    bf16x8 kb0 = *(const bf16x8*)&Kr[h * 64 + lk * 8];
    bf16x8 kb1 = *(const bf16x8*)&Kr[h * 64 + 32 + lk * 8];
    f32x4 a = {};
    a = __builtin_amdgcn_mfma_f32_16x16x32_bf16(qa0, kb0, a, 0, 0, 0);
    a = __builtin_amdgcn_mfma_f32_16x16x32_bf16(qa1, kb1, a, 0, 0, 0);
    s[h] = a;
  }
  // dir2 probs: thread j = jg0+wave*16+l15 (fixed), i = i0+lk*4+r
#pragma unroll
  for (int h = 0; h < H_; h++) {
    float ci = cinvS[h * 64 + wave * 16 + l15];
#pragma unroll
    for (int r = 0; r < 4; r++) s[h][r] = __expf(s[h][r] * SCALE_) * ci;
  }
  // mix + write M2[bg][j-local][i] (b64 per g)
#pragma unroll
  for (int g = 0; g < H_; g++) {
    f32x2 mlo = {0.f, 0.f}, mhi = {0.f, 0.f};
#pragma unroll
    for (int h = 0; h < H_; h++) {
      float w = cthw[g * H_ + h];
      f32x2 slo = {s[h][0], s[h][1]};
      f32x2 shi = {s[h][2], s[h][3]};
      mlo += w * slo;
      mhi += w * shi;
    }
    ushort4 o;
    o.x = f2bf(mlo[0]); o.y = f2bf(mlo[1]); o.z = f2bf(mhi[0]); o.w = f2bf(mhi[1]);
    *(ushort4*)&M2[(((size_t)b * H_ + g) * CJ + jl0 + wave * 16 + l15) * I_ + i0 + lk * 4] = o;
  }
}

// ---------------- PV: batched (b,g) GEMM  C[row,64d] = A[row,K] @ Bt[64,K]^T ----
// grid (rowtiles, 32 bg). A slab per bg = rowsA*K. Bt = vT-type [b][1024][2048].
// mode: 0 = f32 write, 1 = f32 accumulate, 2 = bf16 write.
__global__ __launch_bounds__(256) void pv_gemm(
    const unsigned short* __restrict__ A, const unsigned short* __restrict__ Bt,
    void* __restrict__ outp, int rowsA, int K, int kbase, int orow0, int mode) {
  __shared__ unsigned short As[128 * LDP];
  __shared__ unsigned short Bs[64 * LDP];
  int bg = blockIdx.y, b = bg >> 4, g = bg & 15;
  int t = threadIdx.x, lane = t & 63, wave = t >> 6;
  int l15 = lane & 15, lk = lane >> 4;
  int row0 = blockIdx.x * 128;
  int lrow = t >> 2, lc8 = (t & 3) * 8;
  const unsigned short* Ab = A + (size_t)bg * rowsA * K;
  const unsigned short* Btb = Bt + ((size_t)b * INNER_ + g * 64) * J_ + kbase;
  int wm = wave * 32;
  f32x4 acc[2][4] = {};

  for (int k0 = 0; k0 < K; k0 += 32) {
    int r1 = row0 + lrow;      if (r1 >= rowsA) r1 = rowsA - 1;
    int r2 = row0 + lrow + 64; if (r2 >= rowsA) r2 = rowsA - 1;
    *(bf16x8*)&As[lrow * LDP + lc8]        = *(const bf16x8*)&Ab[(size_t)r1 * K + k0 + lc8];
    *(bf16x8*)&As[(lrow + 64) * LDP + lc8] = *(const bf16x8*)&Ab[(size_t)r2 * K + k0 + lc8];
    if (lrow < 64)
      *(bf16x8*)&Bs[lrow * LDP + lc8] = *(const bf16x8*)&Btb[(size_t)lrow * J_ + k0 + lc8];
    __syncthreads();
    bf16x8 af[2], bfr[4];
#pragma unroll
    for (int mi = 0; mi < 2; mi++) af[mi]  = *(const bf16x8*)&As[(wm + mi * 16 + l15) * LDP + lk * 8];
#pragma unroll
    for (int ni = 0; ni < 4; ni++) bfr[ni] = *(const bf16x8*)&Bs[(ni * 16 + l15) * LDP + lk * 8];
#pragma unroll
    for (int mi = 0; mi < 2; mi++)
#pragma unroll
      for (int ni = 0; ni < 4; ni++)
        acc[mi][ni] = __builtin_amdgcn_mfma_f32_16x16x32_bf16(af[mi], bfr[ni], acc[mi][ni], 0, 0, 0);
    __syncthreads();
  }
#pragma unroll
  for (int mi = 0; mi < 2; mi++)
#pragma unroll
    for (int ni = 0; ni < 4; ni++) {
      int col = g * 64 + ni * 16 + l15;
#pragma unroll
      for (int r = 0; r < 4; r++) {
        int row = row0 + wm + mi * 16 + lk * 4 + r;
        if (row >= rowsA) continue;
        size_t oidx = ((size_t)b * 2048 + orow0 + row) * INNER_ + col;
        float v = acc[mi][ni][r];
        if (mode == 2)      ((unsigned short*)outp)[oidx] = f2bf(v);
        else if (mode == 1) ((float*)outp)[oidx] += v;
        else                ((float*)outp)[oidx] = v;
      }
    }
}

// ---------------- cast f32 -> bf16 ----------------
__global__ __launch_bounds__(256) void cast_kernel(
    const float* __restrict__ in, unsigned short* __restrict__ out, int n4) {
  int idx = blockIdx.x * 256 + threadIdx.x;
  if (idx >= n4) return;
  float4 v = ((const float4*)in)[idx];
  ushort4 o;
  o.x = f2bf(v.x); o.y = f2bf(v.y); o.z = f2bf(v.z); o.w = f2bf(v.w);
  ((ushort4*)out)[idx] = o;
}

// ---------------- launch ----------------
extern "C" void kernel_launch(void* const* d_in, const int* in_sizes, int n_in,
                              void* d_out, int out_size, void* d_ws, size_t ws_size,
                              hipStream_t stream) {
  const float* x      = (const float*)d_in[0];
  const float* ctx    = (const float*)d_in[1];
  const float* ln_g   = (const float*)d_in[2];
  const float* ln_b   = (const float*)d_in[3];
  const float* cln_g  = (const float*)d_in[4];
  const float* cln_b  = (const float*)d_in[5];
  const float* W_qk   = (const float*)d_in[6];
  const float* W_cqk  = (const float*)d_in[7];
  const float* W_v    = (const float*)d_in[8];
  const float* W_cv   = (const float*)d_in[9];
  const float* W_out  = (const float*)d_in[10];
  const float* b_out  = (const float*)d_in[11];
  const float* W_cout = (const float*)d_in[12];
  const float* b_cout = (const float*)d_in[13];
  const float* th_w   = (const float*)d_in[14];
  const float* cth_w  = (const float*)d_in[15];

  char* w = (char*)d_ws;
  const size_t SZ_ROW = (size_t)B_ * I_ * DIM_ * 2;   // 8.39 MB
  const size_t SZ_W   = (size_t)DIM_ * INNER_ * 2;    // 2.1 MB
  unsigned short* xn    = (unsigned short*)w; w += SZ_ROW;   // later: Oh1 bf16, or M1 @ CJ=64
  unsigned short* cn    = (unsigned short*)w; w += SZ_ROW;   // later: Oh2 bf16
  unsigned short* Wqkt  = (unsigned short*)w; w += SZ_W;     // Wqkt..Wcvt later: M2 @ CJ=64
  unsigned short* Wcqkt = (unsigned short*)w; w += SZ_W;
  unsigned short* Wvt   = (unsigned short*)w; w += SZ_W;
  unsigned short* Wcvt  = (unsigned short*)w; w += SZ_W;
  unsigned short* Woutt = (unsigned short*)w; w += SZ_W;
  unsigned short* Wcoutt= (unsigned short*)w; w += SZ_W;
  unsigned short* qk    = (unsigned short*)w; w += SZ_ROW;
  unsigned short* ck    = (unsigned short*)w; w += SZ_ROW;
  unsigned short* vv    = (unsigned short*)w; w += SZ_ROW;   // vv+cv later: OhF1 f32
  unsigned short* cv    = (unsigned short*)w; w += SZ_ROW;
  unsigned short* vT    = (unsigned short*)w; w += SZ_ROW;
  unsigned short* cvT   = (unsigned short*)w; w += SZ_ROW;
  float* rsum = (float*)w; w += (size_t)B_ * H_ * I_ * 4;
  float* csum = (float*)w; w += (size_t)B_ * H_ * J_ * 4;

  // adaptive M-chunk size: M1 (bg x I x CJ) + M2 (bg x CJ x I), bf16 each
  size_t base_end = (size_t)(w - (char*)d_ws);
  size_t tail = (ws_size > base_end) ? ws_size - base_end : 0;
  int CJ = 0;
  for (int cand = 2048; cand >= 128; cand >>= 1)
    if ((size_t)B_ * H_ * I_ * cand * 2 * 2 <= tail) { CJ = cand; break; }
  unsigned short *M1p, *M2p;
  if (CJ) {
    M1p = (unsigned short*)w;
    M2p = (unsigned short*)(w + (size_t)B_ * H_ * I_ * CJ * 2);
  } else {
    CJ = 64;                     // overlay: xn (dead) and Wqkt..Wcvt (dead)
    M1p = xn;
    M2p = Wqkt;
  }
  float* OhF1 = (float*)vv;                 // vv+cv region (16.78 MB)
  unsigned short* Oh1 = xn;                 // final bf16 homes
  unsigned short* Oh2 = cn;

  dim3 tb(32, 8);
  ln_cast_kernel<<<B_ * I_, 256, 0, stream>>>(x, ln_g, ln_b, xn);
  ln_cast_kernel<<<B_ * J_, 256, 0, stream>>>(ctx, cln_g, cln_b, cn);

  transpose_cast_f32<<<dim3(32, 32, 1), tb, 0, stream>>>(W_qk,   Wqkt,  DIM_, INNER_);
  transpose_cast_f32<<<dim3(32, 32, 1), tb, 0, stream>>>(W_cqk,  Wcqkt, DIM_, INNER_);
  transpose_cast_f32<<<dim3(32, 32, 1), tb, 0, stream>>>(W_v,    Wvt,   DIM_, INNER_);
  transpose_cast_f32<<<dim3(32, 32, 1), tb, 0, stream>>>(W_cv,   Wcvt,  DIM_, INNER_);
  transpose_cast_f32<<<dim3(32, 32, 1), tb, 0, stream>>>(W_out,  Woutt, INNER_, DIM_);
  transpose_cast_f32<<<dim3(32, 32, 1), tb, 0, stream>>>(W_cout, Wcoutt,INNER_, DIM_);

  gemm_bt<<<dim3(INNER_ / 128, (B_ * I_) / 128), 256, 0, stream>>>(xn, Wqkt,  nullptr, qk, B_ * I_, INNER_, DIM_, 0);
  gemm_bt<<<dim3(INNER_ / 128, (B_ * J_) / 128), 256, 0, stream>>>(cn, Wcqkt, nullptr, ck, B_ * J_, INNER_, DIM_, 0);
  gemm_bt<<<dim3(INNER_ / 128, (B_ * I_) / 128), 256, 0, stream>>>(xn, Wvt,   nullptr, vv, B_ * I_, INNER_, DIM_, 0);
  gemm_bt<<<dim3(INNER_ / 128, (B_ * J_) / 128), 256, 0, stream>>>(cn, Wcvt,  nullptr, cv, B_ * J_, INNER_, DIM_, 0);

  transpose_bf16<<<dim3(INNER_ / 32, I_ / 32, B_), tb, 0, stream>>>(vv, vT, I_, INNER_);
  transpose_bf16<<<dim3(INNER_ / 32, J_ / 32, B_), tb, 0, stream>>>(cv, cvT, J_, INNER_);

  stats_kernel<<<dim3(I_ / 32, H_, B_), 256, 0, stream>>>(qk, ck, rsum, I_, J_);
  stats_kernel<<<dim3(J_ / 32, H_, B_), 256, 0, stream>>>(ck, qk, csum, J_, I_);

  // ---- attention core: chunked over j ----
  int nch = J_ / CJ;
  for (int c = 0; c < nch; c++) {
    mix_kernel<<<dim3(CJ / 64, I_ / 16, B_), 256, 0, stream>>>(
        qk, ck, rsum, csum, th_w, cth_w, M1p, M2p, c * CJ, CJ);
    // dir1: Oh1F[b,i,gd] (+)= M1[bg,i,jc] @ cvT[b,gd,jc]
    pv_gemm<<<dim3(I_ / 128, B_ * H_), 256, 0, stream>>>(
        M1p, cvT, OhF1, I_, CJ, c * CJ, 0, c ? 1 : 0);
    // dir2: Oh2[b,jc,gd] = M2[bg,jc,i] @ vT[b,gd,i]  (rows partitioned by chunk)
    int rt = CJ >= 128 ? CJ / 128 : 1;
    pv_gemm<<<dim3(rt, B_ * H_), 256, 0, stream>>>(
        M2p, vT, Oh2, CJ, I_, 0, c * CJ, 2);
  }
  const int n4 = (B_ * I_ * INNER_) / 4;
  cast_kernel<<<n4 / 256, 256, 0, stream>>>(OhF1, Oh1, n4);

  gemm_bt<<<dim3(DIM_ / 128, (B_ * I_) / 128), 256, 0, stream>>>(Oh1, Woutt, b_out, (float*)d_out, B_ * I_, DIM_, INNER_, 1);
  gemm_bt<<<dim3(DIM_ / 128, (B_ * J_) / 128), 256, 0, stream>>>(Oh2, Wcoutt, b_cout, ((float*)d_out) + (size_t)B_ * I_ * DIM_, B_ * J_, DIM_, INNER_, 1);
}

// Round 4
// 1258.155 us; speedup vs baseline: 1.0275x; 1.0275x over previous
//
#include <hip/hip_runtime.h>
#include <hip/hip_bf16.h>
#include <cstdint>

#define DIM_   1024
#define H_     16
#define DH_    64
#define INNER_ 1024
#define B_     2
#define I_     2048
#define J_     2048
#define SCALE_ 0.125f

using bf16x8 = __attribute__((ext_vector_type(8))) short;
using f32x4  = __attribute__((ext_vector_type(4))) float;

__device__ __forceinline__ unsigned short f2bf(float f) {
  unsigned int u = __float_as_uint(f);
  u = (u + 0x7FFFu + ((u >> 16) & 1u)) >> 16;
  return (unsigned short)u;
}
__device__ __forceinline__ float bf2f(unsigned short h) {
  return __uint_as_float(((unsigned int)h) << 16);
}

// ---------------- LayerNorm + cast to bf16 ----------------
__global__ __launch_bounds__(256) void ln_cast_kernel(
    const float* __restrict__ in, const float* __restrict__ g,
    const float* __restrict__ bb, unsigned short* __restrict__ out) {
  int row = blockIdx.x;
  int t = threadIdx.x;
  const float4* rp = (const float4*)(in + (size_t)row * DIM_);
  float4 v = rp[t];
  float s  = v.x + v.y + v.z + v.w;
  float ss = v.x * v.x + v.y * v.y + v.z * v.z + v.w * v.w;
  for (int o = 1; o < 64; o <<= 1) {
    s  += __shfl_xor(s, o, 64);
    ss += __shfl_xor(ss, o, 64);
  }
  __shared__ float ls[4], lss[4];
  int wave = t >> 6, lane = t & 63;
  if (lane == 0) { ls[wave] = s; lss[wave] = ss; }
  __syncthreads();
  s  = ls[0] + ls[1] + ls[2] + ls[3];
  ss = lss[0] + lss[1] + lss[2] + lss[3];
  float mu  = s * (1.0f / DIM_);
  float var = ss * (1.0f / DIM_) - mu * mu;
  float rstd = rsqrtf(var + 1e-5f);
  float4 gv = ((const float4*)g)[t];
  float4 bv = ((const float4*)bb)[t];
  ushort4 o4;
  o4.x = f2bf((v.x - mu) * rstd * gv.x + bv.x);
  o4.y = f2bf((v.y - mu) * rstd * gv.y + bv.y);
  o4.z = f2bf((v.z - mu) * rstd * gv.z + bv.z);
  o4.w = f2bf((v.w - mu) * rstd * gv.w + bv.w);
  ((ushort4*)(out + (size_t)row * DIM_))[t] = o4;
}

// ---------------- transpose + cast f32 -> bf16 ----------------
__global__ __launch_bounds__(256) void transpose_cast_f32(
    const float* __restrict__ in, unsigned short* __restrict__ out, int R, int C) {
  __shared__ float tile[32][33];
  int z = blockIdx.z;
  const float* ip = in + (size_t)z * R * C;
  unsigned short* op = out + (size_t)z * R * C;
  int c0 = blockIdx.x * 32, r0 = blockIdx.y * 32;
  int tx = threadIdx.x, ty = threadIdx.y;
  for (int k = 0; k < 4; k++)
    tile[ty * 4 + k][tx] = ip[(size_t)(r0 + ty * 4 + k) * C + c0 + tx];
  __syncthreads();
  for (int k = 0; k < 4; k++)
    op[(size_t)(c0 + ty * 4 + k) * R + r0 + tx] = f2bf(tile[tx][ty * 4 + k]);
}

// ---------------- transpose bf16 -> bf16 ----------------
__global__ __launch_bounds__(256) void transpose_bf16(
    const unsigned short* __restrict__ in, unsigned short* __restrict__ out, int R, int C) {
  __shared__ unsigned short tile[32][33];
  int z = blockIdx.z;
  const unsigned short* ip = in + (size_t)z * R * C;
  unsigned short* op = out + (size_t)z * R * C;
  int c0 = blockIdx.x * 32, r0 = blockIdx.y * 32;
  int tx = threadIdx.x, ty = threadIdx.y;
  for (int k = 0; k < 4; k++)
    tile[ty * 4 + k][tx] = ip[(size_t)(r0 + ty * 4 + k) * C + c0 + tx];
  __syncthreads();
  for (int k = 0; k < 4; k++)
    op[(size_t)(c0 + ty * 4 + k) * R + r0 + tx] = tile[tx][ty * 4 + k];
}

// ---------------- bf16 GEMM: C[M,N] = A[M,K] @ Bt[N,K]^T (+bias) ----------------
#define LDP 40
__global__ __launch_bounds__(256) void gemm_bt(
    const unsigned short* __restrict__ A, const unsigned short* __restrict__ Bt,
    const float* __restrict__ bias, void* __restrict__ Cout,
    int M, int N, int K, int c_f32) {
  __shared__ unsigned short As[128 * LDP];
  __shared__ unsigned short Bs[128 * LDP];
  int t = threadIdx.x;
  int lane = t & 63, wave = t >> 6;
  int m0 = blockIdx.y * 128, n0 = blockIdx.x * 128;
  int wm = (wave >> 1) * 64, wn = (wave & 1) * 64;
  int l15 = lane & 15, lk = lane >> 4;
  int lrow = t >> 2, lc8 = (t & 3) * 8;
  f32x4 acc[4][4] = {};

  for (int k0 = 0; k0 < K; k0 += 32) {
    *(bf16x8*)&As[lrow * LDP + lc8]        = *(const bf16x8*)&A[(size_t)(m0 + lrow) * K + k0 + lc8];
    *(bf16x8*)&As[(lrow + 64) * LDP + lc8] = *(const bf16x8*)&A[(size_t)(m0 + lrow + 64) * K + k0 + lc8];
    *(bf16x8*)&Bs[lrow * LDP + lc8]        = *(const bf16x8*)&Bt[(size_t)(n0 + lrow) * K + k0 + lc8];
    *(bf16x8*)&Bs[(lrow + 64) * LDP + lc8] = *(const bf16x8*)&Bt[(size_t)(n0 + lrow + 64) * K + k0 + lc8];
    __syncthreads();
    bf16x8 af[4], bfr[4];
#pragma unroll
    for (int mi = 0; mi < 4; mi++) af[mi]  = *(const bf16x8*)&As[(wm + mi * 16 + l15) * LDP + lk * 8];
#pragma unroll
    for (int ni = 0; ni < 4; ni++) bfr[ni] = *(const bf16x8*)&Bs[(wn + ni * 16 + l15) * LDP + lk * 8];
#pragma unroll
    for (int mi = 0; mi < 4; mi++)
#pragma unroll
      for (int ni = 0; ni < 4; ni++)
        acc[mi][ni] = __builtin_amdgcn_mfma_f32_16x16x32_bf16(af[mi], bfr[ni], acc[mi][ni], 0, 0, 0);
    __syncthreads();
  }
#pragma unroll
  for (int mi = 0; mi < 4; mi++)
#pragma unroll
    for (int ni = 0; ni < 4; ni++) {
      int col = n0 + wn + ni * 16 + l15;
      float bsv = bias ? bias[col] : 0.0f;
#pragma unroll
      for (int r = 0; r < 4; r++) {
        int row = m0 + wm + mi * 16 + lk * 4 + r;
        float val = acc[mi][ni][r] + bsv;
        if (c_f32) ((float*)Cout)[(size_t)row * N + col] = val;
        else ((unsigned short*)Cout)[(size_t)row * N + col] = f2bf(val);
      }
    }
}

// ---------------- stats: rsum[b,h,i] = sum_j exp(SCALE * dot(...)) ----------------
__global__ __launch_bounds__(256) void stats_kernel(
    const unsigned short* __restrict__ Q, const unsigned short* __restrict__ Kc,
    float* __restrict__ rsum, int NQ, int NK) {
  int b = blockIdx.z, h = blockIdx.y, i0 = blockIdx.x * 32;
  int t = threadIdx.x, lane = t & 63, wave = t >> 6;
  int l15 = lane & 15, lk = lane >> 4;
  const size_t qbase = ((size_t)b * NQ + i0) * INNER_ + h * DH_;
  bf16x8 af[2][2];
#pragma unroll
  for (int mi = 0; mi < 2; mi++)
#pragma unroll
    for (int ks = 0; ks < 2; ks++)
      af[mi][ks] = *(const bf16x8*)&Q[qbase + (size_t)(mi * 16 + l15) * INNER_ + ks * 32 + lk * 8];
  float racc[2][4] = {};
  for (int j0 = wave * 16; j0 < NK; j0 += 64) {
    const size_t kbase = ((size_t)b * NK + j0 + l15) * INNER_ + h * DH_ + lk * 8;
    bf16x8 b0 = *(const bf16x8*)&Kc[kbase];
    bf16x8 b1 = *(const bf16x8*)&Kc[kbase + 32];
#pragma unroll
    for (int mi = 0; mi < 2; mi++) {
      f32x4 acc = {};
      acc = __builtin_amdgcn_mfma_f32_16x16x32_bf16(af[mi][0], b0, acc, 0, 0, 0);
      acc = __builtin_amdgcn_mfma_f32_16x16x32_bf16(af[mi][1], b1, acc, 0, 0, 0);
#pragma unroll
      for (int r = 0; r < 4; r++) racc[mi][r] += __expf(acc[r] * SCALE_);
    }
  }
#pragma unroll
  for (int o = 1; o < 16; o <<= 1)
#pragma unroll
    for (int mi = 0; mi < 2; mi++)
#pragma unroll
      for (int r = 0; r < 4; r++) racc[mi][r] += __shfl_xor(racc[mi][r], o, 64);
  __shared__ float part[4][32];
  if (l15 == 0)
#pragma unroll
    for (int mi = 0; mi < 2; mi++)
#pragma unroll
      for (int r = 0; r < 4; r++) part[wave][mi * 16 + lk * 4 + r] = racc[mi][r];
  __syncthreads();
  if (t < 32)
    rsum[((size_t)b * H_ + h) * NQ + i0 + t] = part[0][t] + part[1][t] + part[2][t] + part[3][t];
}

// ---------------- fused attention: sim -> P^T -> MFMA mix -> PV ----------------
// grid (NQ/16, jsplit, B), 256 thr, 4 waves. Per 64-j iter:
//  phase1 (per wave, 16j strip): sim via MFMA (A=Q m=i, B=K n=j) -> lane holds
//    (im=lk*4+r, jl=l15); exp*rinv; pack bf16 -> write P^T[pos=im*16+jl][h16]
//    to wave-private LDS (2x b128 per r).
//  phase2: 16 mix MFMAs: A=P^T rows (m=pos, k=h dup), B=thw hi|lo bf16 split
//    (k<16 hi, k>=16 residual) -> exact f32 thw. D: n=l15=g, m=lk*4+r=jl.
//    Write b64 to Ms[g*16+im][64j].
//  phase3 (cross-wave): PV as round-2: wave owns 4 g, A-frags from Ms, B=V^T.
#define PH_ 16
#define MJ_ 72
__global__ __launch_bounds__(256, 2) void fused_attn_kernel(
    const unsigned short* __restrict__ Q, const unsigned short* __restrict__ Kc,
    const unsigned short* __restrict__ Vt, const float* __restrict__ rsum,
    const float* __restrict__ thw,
    float* __restrict__ p0, float* __restrict__ p1,
    int NQ, int NK, int CHUNK) {
  __shared__ unsigned short Pb[4 * 256 * PH_];  // 32 KB, wave-private quarters
  __shared__ unsigned short Ms[256 * MJ_];      // 36.9 KB mixed probs
  __shared__ float rinvS[256];
  int jc = blockIdx.y, b = blockIdx.z;
  int i0 = blockIdx.x * 16;
  float* __restrict__ Op = jc ? p1 : p0;
  int t = threadIdx.x, lane = t & 63, wave = t >> 6;
  int l15 = lane & 15, lk = lane >> 4;

  rinvS[t] = 1.0f / rsum[((size_t)b * H_ + (t >> 4)) * NQ + i0 + (t & 15)];

  // thw B-frag: lane (l15=g, lk): k=lk*8+e; h=(lk&1)*8+e; lk<2 -> hi, else residual
  bf16x8 tfrag;
  {
    int part = lk >> 1, hb = (lk & 1) * 8;
#pragma unroll
    for (int e = 0; e < 8; e++) {
      float a = thw[l15 * H_ + hb + e];
      unsigned short hi = f2bf(a);
      tfrag[e] = (short)(part == 0 ? hi : f2bf(a - bf2f(hi)));
    }
  }
  __syncthreads();

  unsigned short* pw = &Pb[wave * 256 * PH_];
  const unsigned short* Qb = Q + ((size_t)b * NQ + i0 + l15) * INNER_;
  f32x4 acc[16] = {};
  const int jbeg = jc * CHUNK;

  for (int js = 0; js < CHUNK; js += 64) {
    int j0 = jbeg + js;
    const unsigned short* Kb = Kc + ((size_t)b * NK + j0 + wave * 16 + l15) * INNER_;
    // ---- phase 1: sim + softmax-normalize -> P^T (wave-private) ----
    unsigned int stage[4][8];
#pragma unroll
    for (int h = 0; h < H_; h++) {
      bf16x8 qa0 = *(const bf16x8*)&Qb[h * 64 + lk * 8];
      bf16x8 qa1 = *(const bf16x8*)&Qb[h * 64 + 32 + lk * 8];
      bf16x8 kb0 = *(const bf16x8*)&Kb[h * 64 + lk * 8];
      bf16x8 kb1 = *(const bf16x8*)&Kb[h * 64 + 32 + lk * 8];
      f32x4 s = {};
      s = __builtin_amdgcn_mfma_f32_16x16x32_bf16(qa0, kb0, s, 0, 0, 0);
      s = __builtin_amdgcn_mfma_f32_16x16x32_bf16(qa1, kb1, s, 0, 0, 0);
      f32x4 ri = *(const f32x4*)&rinvS[h * 16 + lk * 4];
#pragma unroll
      for (int r = 0; r < 4; r++) {
        float e = __expf(s[r] * SCALE_) * ri[r];
        unsigned int bv = f2bf(e);
        if (h & 1) stage[r][h >> 1] |= bv << 16;
        else       stage[r][h >> 1] = bv;
      }
    }
#pragma unroll
    for (int r = 0; r < 4; r++) {
      int row = (lk * 4 + r) * 16 + l15;   // pos = im*16 + jl
      uint4 u0 = {stage[r][0], stage[r][1], stage[r][2], stage[r][3]};
      uint4 u1 = {stage[r][4], stage[r][5], stage[r][6], stage[r][7]};
      *(uint4*)&pw[row * PH_]     = u0;
      *(uint4*)&pw[row * PH_ + 8] = u1;
    }
    // ---- phase 2: MFMA mix (own-wave P^T; compiler orders via lgkmcnt) ----
#pragma unroll
    for (int p = 0; p < 16; p++) {
      bf16x8 af = *(const bf16x8*)&pw[(p * 16 + l15) * PH_ + (lk & 1) * 8];
      f32x4 m = {};
      m = __builtin_amdgcn_mfma_f32_16x16x32_bf16(af, tfrag, m, 0, 0, 0);
      // lane: g = l15, im = p, jl = lk*4 + r
      ushort4 o;
      o.x = f2bf(m[0]); o.y = f2bf(m[1]); o.z = f2bf(m[2]); o.w = f2bf(m[3]);
      *(ushort4*)&Ms[(l15 * 16 + p) * MJ_ + wave * 16 + lk * 4] = o;
    }
    __syncthreads();
    // ---- phase 3: PV (wave owns g = wave*4 .. wave*4+3) ----
#pragma unroll
    for (int gi = 0; gi < 4; gi++) {
      int g = wave * 4 + gi;
      bf16x8 ma0 = *(const bf16x8*)&Ms[(g * 16 + l15) * MJ_ + lk * 8];
      bf16x8 ma1 = *(const bf16x8*)&Ms[(g * 16 + l15) * MJ_ + 32 + lk * 8];
#pragma unroll
      for (int nt = 0; nt < 4; nt++) {
        const size_t vb = ((size_t)b * INNER_ + g * 64 + nt * 16 + l15) * NK + j0 + lk * 8;
        bf16x8 v0 = *(const bf16x8*)&Vt[vb];
        bf16x8 v1 = *(const bf16x8*)&Vt[vb + 32];
        acc[gi * 4 + nt] = __builtin_amdgcn_mfma_f32_16x16x32_bf16(ma0, v0, acc[gi * 4 + nt], 0, 0, 0);
        acc[gi * 4 + nt] = __builtin_amdgcn_mfma_f32_16x16x32_bf16(ma1, v1, acc[gi * 4 + nt], 0, 0, 0);
      }
    }
    __syncthreads();
  }
#pragma unroll
  for (int gi = 0; gi < 4; gi++) {
#pragma unroll
    for (int nt = 0; nt < 4; nt++) {
      int col = (wave * 4 + gi) * 64 + nt * 16 + l15;
#pragma unroll
      for (int r = 0; r < 4; r++)
        Op[((size_t)b * NQ + i0 + lk * 4 + r) * INNER_ + col] = acc[gi * 4 + nt][r];
    }
  }
}

// ---------------- reduce 2 partials + cast to bf16 ----------------
__global__ __launch_bounds__(256) void reduce_cast_kernel(
    const float* __restrict__ p0, const float* __restrict__ p1,
    unsigned short* __restrict__ out, int n4) {
  int idx = blockIdx.x * 256 + threadIdx.x;
  if (idx >= n4) return;
  float4 v = ((const float4*)p0)[idx];
  float4 w = ((const float4*)p1)[idx];
  v.x += w.x; v.y += w.y; v.z += w.z; v.w += w.w;
  ushort4 o;
  o.x = f2bf(v.x); o.y = f2bf(v.y); o.z = f2bf(v.z); o.w = f2bf(v.w);
  ((ushort4*)out)[idx] = o;
}

// ---------------- launch ----------------
extern "C" void kernel_launch(void* const* d_in, const int* in_sizes, int n_in,
                              void* d_out, int out_size, void* d_ws, size_t ws_size,
                              hipStream_t stream) {
  const float* x      = (const float*)d_in[0];
  const float* ctx    = (const float*)d_in[1];
  const float* ln_g   = (const float*)d_in[2];
  const float* ln_b   = (const float*)d_in[3];
  const float* cln_g  = (const float*)d_in[4];
  const float* cln_b  = (const float*)d_in[5];
  const float* W_qk   = (const float*)d_in[6];
  const float* W_cqk  = (const float*)d_in[7];
  const float* W_v    = (const float*)d_in[8];
  const float* W_cv   = (const float*)d_in[9];
  const float* W_out  = (const float*)d_in[10];
  const float* b_out  = (const float*)d_in[11];
  const float* W_cout = (const float*)d_in[12];
  const float* b_cout = (const float*)d_in[13];
  const float* th_w   = (const float*)d_in[14];
  const float* cth_w  = (const float*)d_in[15];

  char* w = (char*)d_ws;
  const size_t SZ_ROW = (size_t)B_ * I_ * DIM_ * 2;   // 8.39 MB
  const size_t SZ_W   = (size_t)DIM_ * INNER_ * 2;    // 2.1 MB
  unsigned short* xn    = (unsigned short*)w; w += SZ_ROW;  // p0 overlay later
  unsigned short* cn    = (unsigned short*)w; w += SZ_ROW;
  unsigned short* Wqkt  = (unsigned short*)w; w += SZ_W;
  unsigned short* Wcqkt = (unsigned short*)w; w += SZ_W;
  unsigned short* Wvt   = (unsigned short*)w; w += SZ_W;
  unsigned short* Wcvt  = (unsigned short*)w; w += SZ_W;
  unsigned short* Woutt = (unsigned short*)w; w += SZ_W;
  unsigned short* Wcoutt= (unsigned short*)w; w += SZ_W;
  unsigned short* qk    = (unsigned short*)w; w += SZ_ROW;
  unsigned short* ck    = (unsigned short*)w; w += SZ_ROW;
  unsigned short* vv    = (unsigned short*)w; w += SZ_ROW;  // p1 overlay later
  unsigned short* cv    = (unsigned short*)w; w += SZ_ROW;
  unsigned short* vT    = (unsigned short*)w; w += SZ_ROW;
  unsigned short* cvT   = (unsigned short*)w; w += SZ_ROW;
  float* rsum = (float*)w; w += (size_t)B_ * H_ * I_ * 4;
  float* csum = (float*)w; w += (size_t)B_ * H_ * J_ * 4;
  unsigned short* Oh1 = (unsigned short*)w; w += SZ_ROW;
  unsigned short* Oh2 = (unsigned short*)w; w += SZ_ROW;

  float* p0 = (float*)xn;   // 16.78 MB over xn+cn (dead after input GEMMs)
  float* p1 = (float*)vv;   // 16.78 MB over vv+cv (dead after transposes)

  dim3 tb(32, 8);
  ln_cast_kernel<<<B_ * I_, 256, 0, stream>>>(x, ln_g, ln_b, xn);
  ln_cast_kernel<<<B_ * J_, 256, 0, stream>>>(ctx, cln_g, cln_b, cn);

  transpose_cast_f32<<<dim3(32, 32, 1), tb, 0, stream>>>(W_qk,   Wqkt,  DIM_, INNER_);
  transpose_cast_f32<<<dim3(32, 32, 1), tb, 0, stream>>>(W_cqk,  Wcqkt, DIM_, INNER_);
  transpose_cast_f32<<<dim3(32, 32, 1), tb, 0, stream>>>(W_v,    Wvt,   DIM_, INNER_);
  transpose_cast_f32<<<dim3(32, 32, 1), tb, 0, stream>>>(W_cv,   Wcvt,  DIM_, INNER_);
  transpose_cast_f32<<<dim3(32, 32, 1), tb, 0, stream>>>(W_out,  Woutt, INNER_, DIM_);
  transpose_cast_f32<<<dim3(32, 32, 1), tb, 0, stream>>>(W_cout, Wcoutt,INNER_, DIM_);

  gemm_bt<<<dim3(INNER_ / 128, (B_ * I_) / 128), 256, 0, stream>>>(xn, Wqkt,  nullptr, qk, B_ * I_, INNER_, DIM_, 0);
  gemm_bt<<<dim3(INNER_ / 128, (B_ * J_) / 128), 256, 0, stream>>>(cn, Wcqkt, nullptr, ck, B_ * J_, INNER_, DIM_, 0);
  gemm_bt<<<dim3(INNER_ / 128, (B_ * I_) / 128), 256, 0, stream>>>(xn, Wvt,   nullptr, vv, B_ * I_, INNER_, DIM_, 0);
  gemm_bt<<<dim3(INNER_ / 128, (B_ * J_) / 128), 256, 0, stream>>>(cn, Wcvt,  nullptr, cv, B_ * J_, INNER_, DIM_, 0);

  transpose_bf16<<<dim3(INNER_ / 32, I_ / 32, B_), tb, 0, stream>>>(vv, vT, I_, INNER_);
  transpose_bf16<<<dim3(INNER_ / 32, J_ / 32, B_), tb, 0, stream>>>(cv, cvT, J_, INNER_);

  stats_kernel<<<dim3(I_ / 32, H_, B_), 256, 0, stream>>>(qk, ck, rsum, I_, J_);
  stats_kernel<<<dim3(J_ / 32, H_, B_), 256, 0, stream>>>(ck, qk, csum, J_, I_);

  const int n4 = (B_ * I_ * INNER_) / 4;
  // dir1: softmax over j, rows i
  fused_attn_kernel<<<dim3(I_ / 16, 2, B_), 256, 0, stream>>>(
      qk, ck, cvT, rsum, th_w, p0, p1, I_, J_, J_ / 2);
  reduce_cast_kernel<<<n4 / 256, 256, 0, stream>>>(p0, p1, Oh1, n4);
  // dir2: softmax over i, rows j
  fused_attn_kernel<<<dim3(J_ / 16, 2, B_), 256, 0, stream>>>(
      ck, qk, vT, csum, cth_w, p0, p1, J_, I_, I_ / 2);
  reduce_cast_kernel<<<n4 / 256, 256, 0, stream>>>(p0, p1, Oh2, n4);

  gemm_bt<<<dim3(DIM_ / 128, (B_ * I_) / 128), 256, 0, stream>>>(Oh1, Woutt, b_out, (float*)d_out, B_ * I_, DIM_, INNER_, 1);
  gemm_bt<<<dim3(DIM_ / 128, (B_ * J_) / 128), 256, 0, stream>>>(Oh2, Wcoutt, b_cout, ((float*)d_out) + (size_t)B_ * I_ * DIM_, B_ * J_, DIM_, INNER_, 1);
}

// Round 5
// 1180.063 us; speedup vs baseline: 1.0955x; 1.0662x over previous
//
#include <hip/hip_runtime.h>
#include <hip/hip_bf16.h>
#include <cstdint>

#define DIM_   1024
#define H_     16
#define DH_    64
#define INNER_ 1024
#define B_     2
#define I_     2048
#define J_     2048
#define SCALE_ 0.125f

using bf16x8 = __attribute__((ext_vector_type(8))) short;
using f32x4  = __attribute__((ext_vector_type(4))) float;

__device__ __forceinline__ unsigned short f2bf(float f) {
  unsigned int u = __float_as_uint(f);
  u = (u + 0x7FFFu + ((u >> 16) & 1u)) >> 16;
  return (unsigned short)u;
}
__device__ __forceinline__ float bf2f(unsigned short h) {
  return __uint_as_float(((unsigned int)h) << 16);
}

// ---------------- LayerNorm + cast to bf16 ----------------
__global__ __launch_bounds__(256) void ln_cast_kernel(
    const float* __restrict__ in, const float* __restrict__ g,
    const float* __restrict__ bb, unsigned short* __restrict__ out) {
  int row = blockIdx.x;
  int t = threadIdx.x;
  const float4* rp = (const float4*)(in + (size_t)row * DIM_);
  float4 v = rp[t];
  float s  = v.x + v.y + v.z + v.w;
  float ss = v.x * v.x + v.y * v.y + v.z * v.z + v.w * v.w;
  for (int o = 1; o < 64; o <<= 1) {
    s  += __shfl_xor(s, o, 64);
    ss += __shfl_xor(ss, o, 64);
  }
  __shared__ float ls[4], lss[4];
  int wave = t >> 6, lane = t & 63;
  if (lane == 0) { ls[wave] = s; lss[wave] = ss; }
  __syncthreads();
  s  = ls[0] + ls[1] + ls[2] + ls[3];
  ss = lss[0] + lss[1] + lss[2] + lss[3];
  float mu  = s * (1.0f / DIM_);
  float var = ss * (1.0f / DIM_) - mu * mu;
  float rstd = rsqrtf(var + 1e-5f);
  float4 gv = ((const float4*)g)[t];
  float4 bv = ((const float4*)bb)[t];
  ushort4 o4;
  o4.x = f2bf((v.x - mu) * rstd * gv.x + bv.x);
  o4.y = f2bf((v.y - mu) * rstd * gv.y + bv.y);
  o4.z = f2bf((v.z - mu) * rstd * gv.z + bv.z);
  o4.w = f2bf((v.w - mu) * rstd * gv.w + bv.w);
  ((ushort4*)(out + (size_t)row * DIM_))[t] = o4;
}

// ---------------- transpose + cast f32 -> bf16 ----------------
__global__ __launch_bounds__(256) void transpose_cast_f32(
    const float* __restrict__ in, unsigned short* __restrict__ out, int R, int C) {
  __shared__ float tile[32][33];
  int z = blockIdx.z;
  const float* ip = in + (size_t)z * R * C;
  unsigned short* op = out + (size_t)z * R * C;
  int c0 = blockIdx.x * 32, r0 = blockIdx.y * 32;
  int tx = threadIdx.x, ty = threadIdx.y;
  for (int k = 0; k < 4; k++)
    tile[ty * 4 + k][tx] = ip[(size_t)(r0 + ty * 4 + k) * C + c0 + tx];
  __syncthreads();
  for (int k = 0; k < 4; k++)
    op[(size_t)(c0 + ty * 4 + k) * R + r0 + tx] = f2bf(tile[tx][ty * 4 + k]);
}

// ---------------- transpose bf16 -> bf16 ----------------
__global__ __launch_bounds__(256) void transpose_bf16(
    const unsigned short* __restrict__ in, unsigned short* __restrict__ out, int R, int C) {
  __shared__ unsigned short tile[32][33];
  int z = blockIdx.z;
  const unsigned short* ip = in + (size_t)z * R * C;
  unsigned short* op = out + (size_t)z * R * C;
  int c0 = blockIdx.x * 32, r0 = blockIdx.y * 32;
  int tx = threadIdx.x, ty = threadIdx.y;
  for (int k = 0; k < 4; k++)
    tile[ty * 4 + k][tx] = ip[(size_t)(r0 + ty * 4 + k) * C + c0 + tx];
  __syncthreads();
  for (int k = 0; k < 4; k++)
    op[(size_t)(c0 + ty * 4 + k) * R + r0 + tx] = tile[tx][ty * 4 + k];
}

// ---------------- bf16 GEMM: C[M,N] = A[M,K] @ Bt[N,K]^T (+bias) ----------------
#define LDP 40
__global__ __launch_bounds__(256) void gemm_bt(
    const unsigned short* __restrict__ A, const unsigned short* __restrict__ Bt,
    const float* __restrict__ bias, void* __restrict__ Cout,
    int M, int N, int K, int c_f32) {
  __shared__ unsigned short As[128 * LDP];
  __shared__ unsigned short Bs[128 * LDP];
  int t = threadIdx.x;
  int lane = t & 63, wave = t >> 6;
  int m0 = blockIdx.y * 128, n0 = blockIdx.x * 128;
  int wm = (wave >> 1) * 64, wn = (wave & 1) * 64;
  int l15 = lane & 15, lk = lane >> 4;
  int lrow = t >> 2, lc8 = (t & 3) * 8;
  f32x4 acc[4][4] = {};

  for (int k0 = 0; k0 < K; k0 += 32) {
    *(bf16x8*)&As[lrow * LDP + lc8]        = *(const bf16x8*)&A[(size_t)(m0 + lrow) * K + k0 + lc8];
    *(bf16x8*)&As[(lrow + 64) * LDP + lc8] = *(const bf16x8*)&A[(size_t)(m0 + lrow + 64) * K + k0 + lc8];
    *(bf16x8*)&Bs[lrow * LDP + lc8]        = *(const bf16x8*)&Bt[(size_t)(n0 + lrow) * K + k0 + lc8];
    *(bf16x8*)&Bs[(lrow + 64) * LDP + lc8] = *(const bf16x8*)&Bt[(size_t)(n0 + lrow + 64) * K + k0 + lc8];
    __syncthreads();
    bf16x8 af[4], bfr[4];
#pragma unroll
    for (int mi = 0; mi < 4; mi++) af[mi]  = *(const bf16x8*)&As[(wm + mi * 16 + l15) * LDP + lk * 8];
#pragma unroll
    for (int ni = 0; ni < 4; ni++) bfr[ni] = *(const bf16x8*)&Bs[(wn + ni * 16 + l15) * LDP + lk * 8];
#pragma unroll
    for (int mi = 0; mi < 4; mi++)
#pragma unroll
      for (int ni = 0; ni < 4; ni++)
        acc[mi][ni] = __builtin_amdgcn_mfma_f32_16x16x32_bf16(af[mi], bfr[ni], acc[mi][ni], 0, 0, 0);
    __syncthreads();
  }
#pragma unroll
  for (int mi = 0; mi < 4; mi++)
#pragma unroll
    for (int ni = 0; ni < 4; ni++) {
      int col = n0 + wn + ni * 16 + l15;
      float bsv = bias ? bias[col] : 0.0f;
#pragma unroll
      for (int r = 0; r < 4; r++) {
        int row = m0 + wm + mi * 16 + lk * 4 + r;
        float val = acc[mi][ni][r] + bsv;
        if (c_f32) ((float*)Cout)[(size_t)row * N + col] = val;
        else ((unsigned short*)Cout)[(size_t)row * N + col] = f2bf(val);
      }
    }
}

// ---------------- stats: rsum[b,h,i] = sum_j exp(SCALE * dot(...)) ----------------
__global__ __launch_bounds__(256) void stats_kernel(
    const unsigned short* __restrict__ Q, const unsigned short* __restrict__ Kc,
    float* __restrict__ rsum, int NQ, int NK) {
  int b = blockIdx.z, h = blockIdx.y, i0 = blockIdx.x * 32;
  int t = threadIdx.x, lane = t & 63, wave = t >> 6;
  int l15 = lane & 15, lk = lane >> 4;
  const size_t qbase = ((size_t)b * NQ + i0) * INNER_ + h * DH_;
  bf16x8 af[2][2];
#pragma unroll
  for (int mi = 0; mi < 2; mi++)
#pragma unroll
    for (int ks = 0; ks < 2; ks++)
      af[mi][ks] = *(const bf16x8*)&Q[qbase + (size_t)(mi * 16 + l15) * INNER_ + ks * 32 + lk * 8];
  float racc[2][4] = {};
  for (int j0 = wave * 16; j0 < NK; j0 += 64) {
    const size_t kbase = ((size_t)b * NK + j0 + l15) * INNER_ + h * DH_ + lk * 8;
    bf16x8 b0 = *(const bf16x8*)&Kc[kbase];
    bf16x8 b1 = *(const bf16x8*)&Kc[kbase + 32];
#pragma unroll
    for (int mi = 0; mi < 2; mi++) {
      f32x4 acc = {};
      acc = __builtin_amdgcn_mfma_f32_16x16x32_bf16(af[mi][0], b0, acc, 0, 0, 0);
      acc = __builtin_amdgcn_mfma_f32_16x16x32_bf16(af[mi][1], b1, acc, 0, 0, 0);
#pragma unroll
      for (int r = 0; r < 4; r++) racc[mi][r] += __expf(acc[r] * SCALE_);
    }
  }
#pragma unroll
  for (int o = 1; o < 16; o <<= 1)
#pragma unroll
    for (int mi = 0; mi < 2; mi++)
#pragma unroll
      for (int r = 0; r < 4; r++) racc[mi][r] += __shfl_xor(racc[mi][r], o, 64);
  __shared__ float part[4][32];
  if (l15 == 0)
#pragma unroll
    for (int mi = 0; mi < 2; mi++)
#pragma unroll
      for (int r = 0; r < 4; r++) part[wave][mi * 16 + lk * 4 + r] = racc[mi][r];
  __syncthreads();
  if (t < 32)
    rsum[((size_t)b * H_ + h) * NQ + i0 + t] = part[0][t] + part[1][t] + part[2][t] + part[3][t];
}

// ---------------- fused attention: 32-i tile, 32-j iter, XCD-pinned ----------------
// 1-D grid of 512: combo = n&7 -> (b = combo>>2, jc = combo&3); round-robin
// block->XCD dispatch pins each (b,jc) working set (K 1MB + Vt 1MB) to one XCD L2.
// Block: 256 thr, 4 waves; wave = (isub = w&1, jstrip = w>>1).
// Per 32-j iter: phase1 sim (16i x 16j per wave, all 16 h) -> exp*rinv ->
// P^T[pos][h16] to XOR-swizzled wave-private Pb; phase2: 16 mix-MFMAs
// (B = thw hi|residual bf16 split, exact) -> Ms[g][32i][32j]; phase3: PV,
// wave owns 4 g over both isubs (acc 32 x f32x4 = 128 regs).
#define MSROW 40
#define MSG   (32 * MSROW + 8)   // 1288 shorts per g; +8 breaks g-stride %32 banks
__global__ __launch_bounds__(256, 2) void fused_attn_kernel(
    const unsigned short* __restrict__ Q, const unsigned short* __restrict__ Kc,
    const unsigned short* __restrict__ Vt, const float* __restrict__ rsum,
    const float* __restrict__ thw,
    float* __restrict__ p0, float* __restrict__ p1,
    float* __restrict__ p2, float* __restrict__ p3,
    int NQ, int NK, int CHUNK) {
  __shared__ unsigned short Pb[4 * 256 * 16];   // 32 KB, wave-private quarters
  __shared__ unsigned short Ms[16 * MSG];       // 41.2 KB
  __shared__ float rinvS[512];                  // [h][i 32]
  int n = blockIdx.x;
  int combo = n & 7;
  int b = combo >> 2, jc = combo & 3;
  int i0 = (n >> 3) * 32;
  float* __restrict__ Op = (jc == 0) ? p0 : (jc == 1) ? p1 : (jc == 2) ? p2 : p3;
  int t = threadIdx.x, lane = t & 63, wave = t >> 6;
  int l15 = lane & 15, lk = lane >> 4;
  int isub = wave & 1, jstrip = wave >> 1;

  rinvS[t]       = 1.0f / rsum[((size_t)b * H_ + (t >> 5)) * NQ + i0 + (t & 31)];
  rinvS[t + 256] = 1.0f / rsum[((size_t)b * H_ + ((t + 256) >> 5)) * NQ + i0 + (t & 31)];

  // thw B-frag: lane (l15=g, lk): k=lk*8+e; h=(lk&1)*8+e; lk<2 -> hi, else residual
  bf16x8 tfrag;
  {
    int part = lk >> 1, hb = (lk & 1) * 8;
#pragma unroll
    for (int e = 0; e < 8; e++) {
      float a = thw[l15 * H_ + hb + e];
      unsigned short hi = f2bf(a);
      tfrag[e] = (short)(part == 0 ? hi : f2bf(a - bf2f(hi)));
    }
  }
  __syncthreads();

  unsigned short* pw = &Pb[wave * 256 * 16];
  int qo = 0;
  asm volatile("" : "+v"(qo));  // defeat hoist of Q loads across j-loop
  const unsigned short* Qb = Q + ((size_t)b * NQ + i0 + isub * 16 + l15) * INNER_ + qo;
  f32x4 acc[32] = {};  // [gi*8 + is*4 + nt]
  const int jbeg = jc * CHUNK;

  for (int js = 0; js < CHUNK; js += 32) {
    int j0 = jbeg + js;
    const unsigned short* Kb = Kc + ((size_t)b * NK + j0 + jstrip * 16 + l15) * INNER_;
    // ---- phase 1: sim + normalize -> P^T (wave-private, xor-swizzled) ----
#pragma unroll
    for (int hg = 0; hg < 2; hg++) {
      unsigned int stage[4][4];
#pragma unroll
      for (int hh = 0; hh < 8; hh++) {
        int h = hg * 8 + hh;
        bf16x8 qa0 = *(const bf16x8*)&Qb[h * 64 + lk * 8];
        bf16x8 qa1 = *(const bf16x8*)&Qb[h * 64 + 32 + lk * 8];
        bf16x8 kb0 = *(const bf16x8*)&Kb[h * 64 + lk * 8];
        bf16x8 kb1 = *(const bf16x8*)&Kb[h * 64 + 32 + lk * 8];
        f32x4 s = {};
        s = __builtin_amdgcn_mfma_f32_16x16x32_bf16(qa0, kb0, s, 0, 0, 0);
        s = __builtin_amdgcn_mfma_f32_16x16x32_bf16(qa1, kb1, s, 0, 0, 0);
        f32x4 ri = *(const f32x4*)&rinvS[h * 32 + isub * 16 + lk * 4];
#pragma unroll
        for (int r = 0; r < 4; r++) {
          float e = __expf(s[r] * SCALE_) * ri[r];
          unsigned int bv = f2bf(e);
          if (hh & 1) stage[r][hh >> 1] |= bv << 16;
          else        stage[r][hh >> 1] = bv;
        }
      }
#pragma unroll
      for (int r = 0; r < 4; r++) {
        int row = (lk * 4 + r) * 16 + l15;          // pos = im*16 + jl
        int col = (hg * 8) ^ ((row & 1) << 3);      // xor-swizzle banks
        uint4 u = {stage[r][0], stage[r][1], stage[r][2], stage[r][3]};
        *(uint4*)&pw[row * 16 + col] = u;
      }
    }
    // ---- phase 2: MFMA mix (own-wave Pb; ordered via lgkmcnt) ----
#pragma unroll
    for (int p = 0; p < 16; p++) {
      int row = p * 16 + l15;
      int col = ((lk & 1) << 3) ^ ((row & 1) << 3);
      bf16x8 af = *(const bf16x8*)&pw[row * 16 + col];
      f32x4 m = {};
      m = __builtin_amdgcn_mfma_f32_16x16x32_bf16(af, tfrag, m, 0, 0, 0);
      // lane: g = l15, im = p (within isub), jl = lk*4 + r
      ushort4 o;
      o.x = f2bf(m[0]); o.y = f2bf(m[1]); o.z = f2bf(m[2]); o.w = f2bf(m[3]);
      *(ushort4*)&Ms[l15 * MSG + (isub * 16 + p) * MSROW + jstrip * 16 + lk * 4] = o;
    }
    __syncthreads();
    // ---- phase 3: PV (wave owns g = wave*4..+3, both isubs) ----
#pragma unroll
    for (int gi = 0; gi < 4; gi++) {
      int g = wave * 4 + gi;
      bf16x8 ma0 = *(const bf16x8*)&Ms[g * MSG + l15 * MSROW + lk * 8];
      bf16x8 ma1 = *(const bf16x8*)&Ms[g * MSG + (16 + l15) * MSROW + lk * 8];
#pragma unroll
      for (int nt = 0; nt < 4; nt++) {
        const size_t vb = ((size_t)b * INNER_ + g * 64 + nt * 16 + l15) * NK + j0 + lk * 8;
        bf16x8 v0 = *(const bf16x8*)&Vt[vb];
        acc[gi * 8 + nt]     = __builtin_amdgcn_mfma_f32_16x16x32_bf16(ma0, v0, acc[gi * 8 + nt], 0, 0, 0);
        acc[gi * 8 + 4 + nt] = __builtin_amdgcn_mfma_f32_16x16x32_bf16(ma1, v0, acc[gi * 8 + 4 + nt], 0, 0, 0);
      }
    }
    __syncthreads();
  }
#pragma unroll
  for (int gi = 0; gi < 4; gi++)
#pragma unroll
    for (int is = 0; is < 2; is++)
#pragma unroll
      for (int nt = 0; nt < 4; nt++) {
        int col = (wave * 4 + gi) * 64 + nt * 16 + l15;
#pragma unroll
        for (int r = 0; r < 4; r++)
          Op[((size_t)b * NQ + i0 + is * 16 + lk * 4 + r) * INNER_ + col] = acc[gi * 8 + is * 4 + nt][r];
      }
}

// ---------------- reduce 4 partials + cast to bf16 ----------------
__global__ __launch_bounds__(256) void reduce_cast_kernel(
    const float* __restrict__ p0, const float* __restrict__ p1,
    const float* __restrict__ p2, const float* __restrict__ p3,
    unsigned short* __restrict__ out, int n4) {
  int idx = blockIdx.x * 256 + threadIdx.x;
  if (idx >= n4) return;
  float4 v = ((const float4*)p0)[idx];
  float4 w = ((const float4*)p1)[idx];
  float4 a = ((const float4*)p2)[idx];
  float4 c = ((const float4*)p3)[idx];
  v.x += w.x + a.x + c.x; v.y += w.y + a.y + c.y;
  v.z += w.z + a.z + c.z; v.w += w.w + a.w + c.w;
  ushort4 o;
  o.x = f2bf(v.x); o.y = f2bf(v.y); o.z = f2bf(v.z); o.w = f2bf(v.w);
  ((ushort4*)out)[idx] = o;
}

// ---------------- launch ----------------
extern "C" void kernel_launch(void* const* d_in, const int* in_sizes, int n_in,
                              void* d_out, int out_size, void* d_ws, size_t ws_size,
                              hipStream_t stream) {
  const float* x      = (const float*)d_in[0];
  const float* ctx    = (const float*)d_in[1];
  const float* ln_g   = (const float*)d_in[2];
  const float* ln_b   = (const float*)d_in[3];
  const float* cln_g  = (const float*)d_in[4];
  const float* cln_b  = (const float*)d_in[5];
  const float* W_qk   = (const float*)d_in[6];
  const float* W_cqk  = (const float*)d_in[7];
  const float* W_v    = (const float*)d_in[8];
  const float* W_cv   = (const float*)d_in[9];
  const float* W_out  = (const float*)d_in[10];
  const float* b_out  = (const float*)d_in[11];
  const float* W_cout = (const float*)d_in[12];
  const float* b_cout = (const float*)d_in[13];
  const float* th_w   = (const float*)d_in[14];
  const float* cth_w  = (const float*)d_in[15];

  char* w = (char*)d_ws;
  const size_t SZ_ROW = (size_t)B_ * I_ * DIM_ * 2;   // 8.39 MB
  const size_t SZ_W   = (size_t)DIM_ * INNER_ * 2;    // 2.1 MB
  unsigned short* xn    = (unsigned short*)w; w += SZ_ROW;  // p0 overlay later
  unsigned short* cn    = (unsigned short*)w; w += SZ_ROW;
  unsigned short* Wqkt  = (unsigned short*)w; w += SZ_W;
  unsigned short* Wcqkt = (unsigned short*)w; w += SZ_W;
  unsigned short* Wvt   = (unsigned short*)w; w += SZ_W;
  unsigned short* Wcvt  = (unsigned short*)w; w += SZ_W;
  unsigned short* Woutt = (unsigned short*)w; w += SZ_W;
  unsigned short* Wcoutt= (unsigned short*)w; w += SZ_W;
  unsigned short* qk    = (unsigned short*)w; w += SZ_ROW;
  unsigned short* ck    = (unsigned short*)w; w += SZ_ROW;
  unsigned short* vv    = (unsigned short*)w; w += SZ_ROW;  // p1 overlay later
  unsigned short* cv    = (unsigned short*)w; w += SZ_ROW;
  unsigned short* vT    = (unsigned short*)w; w += SZ_ROW;
  unsigned short* cvT   = (unsigned short*)w; w += SZ_ROW;
  float* rsum = (float*)w; w += (size_t)B_ * H_ * I_ * 4;
  float* csum = (float*)w; w += (size_t)B_ * H_ * J_ * 4;
  unsigned short* Oh1 = (unsigned short*)w; w += SZ_ROW;
  unsigned short* Oh2 = (unsigned short*)w; w += SZ_ROW;

  // 4 partial buffers (16.78 MB each): p0 over xn+cn (dead after input GEMMs),
  // p1 over vv+cv (dead after transposes), p2/p3 fresh tail (fits: verified r2).
  const size_t PART = (size_t)B_ * I_ * INNER_ * 4;
  float* p0 = (float*)xn;
  float* p1 = (float*)vv;
  float* p2 = (float*)w;
  float* p3 = (float*)(w + PART);

  dim3 tb(32, 8);
  ln_cast_kernel<<<B_ * I_, 256, 0, stream>>>(x, ln_g, ln_b, xn);
  ln_cast_kernel<<<B_ * J_, 256, 0, stream>>>(ctx, cln_g, cln_b, cn);

  transpose_cast_f32<<<dim3(32, 32, 1), tb, 0, stream>>>(W_qk,   Wqkt,  DIM_, INNER_);
  transpose_cast_f32<<<dim3(32, 32, 1), tb, 0, stream>>>(W_cqk,  Wcqkt, DIM_, INNER_);
  transpose_cast_f32<<<dim3(32, 32, 1), tb, 0, stream>>>(W_v,    Wvt,   DIM_, INNER_);
  transpose_cast_f32<<<dim3(32, 32, 1), tb, 0, stream>>>(W_cv,   Wcvt,  DIM_, INNER_);
  transpose_cast_f32<<<dim3(32, 32, 1), tb, 0, stream>>>(W_out,  Woutt, INNER_, DIM_);
  transpose_cast_f32<<<dim3(32, 32, 1), tb, 0, stream>>>(W_cout, Wcoutt,INNER_, DIM_);

  gemm_bt<<<dim3(INNER_ / 128, (B_ * I_) / 128), 256, 0, stream>>>(xn, Wqkt,  nullptr, qk, B_ * I_, INNER_, DIM_, 0);
  gemm_bt<<<dim3(INNER_ / 128, (B_ * J_) / 128), 256, 0, stream>>>(cn, Wcqkt, nullptr, ck, B_ * J_, INNER_, DIM_, 0);
  gemm_bt<<<dim3(INNER_ / 128, (B_ * I_) / 128), 256, 0, stream>>>(xn, Wvt,   nullptr, vv, B_ * I_, INNER_, DIM_, 0);
  gemm_bt<<<dim3(INNER_ / 128, (B_ * J_) / 128), 256, 0, stream>>>(cn, Wcvt,  nullptr, cv, B_ * J_, INNER_, DIM_, 0);

  transpose_bf16<<<dim3(INNER_ / 32, I_ / 32, B_), tb, 0, stream>>>(vv, vT, I_, INNER_);
  transpose_bf16<<<dim3(INNER_ / 32, J_ / 32, B_), tb, 0, stream>>>(cv, cvT, J_, INNER_);

  stats_kernel<<<dim3(I_ / 32, H_, B_), 256, 0, stream>>>(qk, ck, rsum, I_, J_);
  stats_kernel<<<dim3(J_ / 32, H_, B_), 256, 0, stream>>>(ck, qk, csum, J_, I_);

  const int n4 = (B_ * I_ * INNER_) / 4;
  // dir1: softmax over j, rows i
  fused_attn_kernel<<<(I_ / 32) * 4 * B_, 256, 0, stream>>>(
      qk, ck, cvT, rsum, th_w, p0, p1, p2, p3, I_, J_, J_ / 4);
  reduce_cast_kernel<<<n4 / 256, 256, 0, stream>>>(p0, p1, p2, p3, Oh1, n4);
  // dir2: softmax over i, rows j
  fused_attn_kernel<<<(J_ / 32) * 4 * B_, 256, 0, stream>>>(
      ck, qk, vT, csum, cth_w, p0, p1, p2, p3, J_, I_, I_ / 4);
  reduce_cast_kernel<<<n4 / 256, 256, 0, stream>>>(p0, p1, p2, p3, Oh2, n4);

  gemm_bt<<<dim3(DIM_ / 128, (B_ * I_) / 128), 256, 0, stream>>>(Oh1, Woutt, b_out, (float*)d_out, B_ * I_, DIM_, INNER_, 1);
  gemm_bt<<<dim3(DIM_ / 128, (B_ * J_) / 128), 256, 0, stream>>>(Oh2, Wcoutt, b_cout, ((float*)d_out) + (size_t)B_ * I_ * DIM_, B_ * J_, DIM_, INNER_, 1);
}